// Round 1
// baseline (5810.641 us; speedup 1.0000x reference)
//
#include <hip/hip_runtime.h>
#include <hip/hip_bf16.h>
#include <math.h>

using bf16 = __hip_bfloat16;
using bf162 = __hip_bfloat162;
typedef __attribute__((ext_vector_type(8))) short frag_ab;   // 8 bf16 (4 VGPRs)
typedef __attribute__((ext_vector_type(4))) float frag_cd;   // 4 fp32 acc

#define NUM_HEADS 16
#define KV_GROUPS 4
#define SEQ 2048
#define BATCH 4
#define FDIM 2048
#define DH 128
#define NQKV 3072   // H*DH + G*DH + G*DH

// ---------------- fp32 -> bf16 convert (vec4) ----------------
__global__ __launch_bounds__(256) void cvt_f32_bf16(const float* __restrict__ in,
                                                    bf16* __restrict__ out, int n4) {
  int i = blockIdx.x * 256 + threadIdx.x;
  if (i >= n4) return;
  float4 v = ((const float4*)in)[i];
  bf162 a; a.x = __float2bfloat16(v.x); a.y = __float2bfloat16(v.y);
  bf162 b; b.x = __float2bfloat16(v.z); b.y = __float2bfloat16(v.w);
  ((bf162*)out)[2 * i]     = a;
  ((bf162*)out)[2 * i + 1] = b;
}

// ---------------- pack [wq|wk|wv] -> (2048 x 3072) bf16 ----------------
__global__ __launch_bounds__(256) void pack_wqkv(const float* __restrict__ wq,
                                                 const float* __restrict__ wk,
                                                 const float* __restrict__ wv,
                                                 bf16* __restrict__ W) {
  int idx = blockIdx.x * 256 + threadIdx.x;
  if (idx >= FDIM * NQKV) return;
  int k = idx / NQKV, n = idx % NQKV;
  float v;
  if (n < 2048)       v = wq[(size_t)k * 2048 + n];
  else if (n < 2560)  v = wk[(size_t)k * 512 + (n - 2048)];
  else                v = wv[(size_t)k * 512 + (n - 2560)];
  W[idx] = __float2bfloat16(v);
}

// ---------------- bf16 MFMA GEMM: C[M,N] = A[M,K] * B[K,N] (+bias) ----------------
// block: 256 thr = 4 waves; tile 64x64, BK=32. wave w -> rows [w*16, w*16+16)
template <int OUTBF>
__global__ __launch_bounds__(256) void gemm64(const bf16* __restrict__ A,
                                              const bf16* __restrict__ B,
                                              void* __restrict__ Cout,
                                              const float* __restrict__ bias,
                                              int M, int N, int K) {
  __shared__ bf16 lds_a[64 * 32];    // [m][k]
  __shared__ bf16 lds_bT[64 * 32];   // [n][k] (transposed so frag reads are contiguous)
  const int tid  = threadIdx.x;
  const int wave = tid >> 6, lane = tid & 63;
  const int quad = lane >> 4, l16 = lane & 15;
  const int m0 = blockIdx.x * 64, n0 = blockIdx.y * 64;

  frag_cd acc[4];
#pragma unroll
  for (int i = 0; i < 4; i++) acc[i] = (frag_cd){0.f, 0.f, 0.f, 0.f};

  const int ar = tid >> 2, ac = (tid & 3) * 8;   // A stage: 64 rows x 32 cols
  const int br = tid >> 3, bc = (tid & 7) * 8;   // B stage: 32 rows x 64 cols

  for (int k0 = 0; k0 < K; k0 += 32) {
    int4 av = *(const int4*)(A + (size_t)(m0 + ar) * K + (k0 + ac));
    int4 bv = *(const int4*)(B + (size_t)(k0 + br) * N + (n0 + bc));
    __syncthreads();   // previous iteration's LDS reads done
    *(int4*)&lds_a[ar * 32 + ac] = av;
    union { int4 v; bf16 h[8]; } u; u.v = bv;
#pragma unroll
    for (int i = 0; i < 8; i++) lds_bT[(bc + i) * 32 + br] = u.h[i];
    __syncthreads();
    // a_frag: A[m = wave*16 + l16][k = quad*8 + j]
    frag_ab af = *(const frag_ab*)&lds_a[(wave * 16 + l16) * 32 + quad * 8];
#pragma unroll
    for (int nt = 0; nt < 4; nt++) {
      // b_frag: B[k = quad*8 + j][n = nt*16 + l16]  (read from transposed LDS)
      frag_ab bf = *(const frag_ab*)&lds_bT[(nt * 16 + l16) * 32 + quad * 8];
      acc[nt] = __builtin_amdgcn_mfma_f32_16x16x32_bf16(af, bf, acc[nt], 0, 0, 0);
    }
  }
  // C/D layout: col = l16, row = quad*4 + r
#pragma unroll
  for (int nt = 0; nt < 4; nt++) {
#pragma unroll
    for (int r = 0; r < 4; r++) {
      int row = m0 + wave * 16 + quad * 4 + r;
      int col = n0 + nt * 16 + l16;
      float v = acc[nt][r];
      if (bias) v += bias[col];
      if (OUTBF) ((bf16*)Cout)[(size_t)row * N + col] = __float2bfloat16(v);
      else       ((float*)Cout)[(size_t)row * N + col] = v;
    }
  }
}

// ---------------- bias + RoPE + scale + scatter to (B,{H|G},S,Dh) bf16 ----------------
// one wave per head-row; lane i handles dims (2i, 2i+1)
__global__ __launch_bounds__(256) void rope_scatter(const bf16* __restrict__ qkv,
                                                    const float* __restrict__ bq,
                                                    const float* __restrict__ bk,
                                                    const float* __restrict__ bv,
                                                    bf16* __restrict__ Q,
                                                    bf16* __restrict__ K,
                                                    bf16* __restrict__ V) {
  int hrg  = blockIdx.x * 4 + (threadIdx.x >> 6);
  int lane = threadIdx.x & 63;
  int hr  = hrg % 24;        // 0..15 q-head, 16..19 k-group, 20..23 v-group
  int row = hrg / 24;        // b*SEQ + s
  int b = row >> 11, s = row & 2047;
  int kind, idx;
  if (hr < 16)      { kind = 0; idx = hr; }
  else if (hr < 20) { kind = 1; idx = hr - 16; }
  else              { kind = 2; idx = hr - 20; }
  int colbase = (kind == 0) ? idx * 128 : (kind == 1 ? 2048 + idx * 128 : 2560 + idx * 128);
  const bf16* src = qkv + (size_t)row * NQKV + colbase;
  bf162 xv = *(const bf162*)(src + 2 * lane);
  float a  = __bfloat162float(xv.x);
  float bb = __bfloat162float(xv.y);
  const float* bias = (kind == 0) ? bq : (kind == 1 ? bk : bv);
  a  += bias[idx * 128 + 2 * lane];
  bb += bias[idx * 128 + 2 * lane + 1];
  if (kind != 2 && lane < 32) {
    // rope pair i=lane, freq = 10000^(-i/32), angle = s * freq
    float freq = powf(10000.f, -(float)lane / 32.f);
    float ang  = (float)s * freq;
    float c = cosf(ang), sn = sinf(ang);
    float na = a * c - bb * sn;
    float nb = bb * c + a * sn;
    a = na; bb = nb;
  }
  if (kind == 0) { a *= 0.08838834764831845f; bb *= 0.08838834764831845f; } // 1/sqrt(128) folded into Q
  bf16* dst;
  if (kind == 0)      dst = Q + ((size_t)((b * NUM_HEADS + idx) * SEQ + s)) * DH;
  else if (kind == 1) dst = K + ((size_t)((b * KV_GROUPS + idx) * SEQ + s)) * DH;
  else                dst = V + ((size_t)((b * KV_GROUPS + idx) * SEQ + s)) * DH;
  bf162 ov; ov.x = __float2bfloat16(a); ov.y = __float2bfloat16(bb);
  *(bf162*)(dst + 2 * lane) = ov;
}

// ---------------- vector flash attention: one wave per (b,h,s) query row ----------------
// No __syncthreads anywhere: waves in a block have different trip counts.
__global__ __launch_bounds__(256) void attn_vec(const bf16* __restrict__ Q,
                                                const bf16* __restrict__ K,
                                                const bf16* __restrict__ V,
                                                bf16* __restrict__ O) {
  __shared__ float q_lds[4][128];
  int wave = threadIdx.x >> 6, lane = threadIdx.x & 63;
  int g = blockIdx.x * 4 + wave;          // (b*H + h)*SEQ + s
  int s = g & 2047;
  int bh = g >> 11;
  int h = bh & 15, b = bh >> 4;
  int grp = h >> 2;                        // GQA: head h -> group h/4
  const bf16* qrow  = Q + (size_t)g * DH;
  const bf16* Kbase = K + (size_t)((b * KV_GROUPS + grp) * SEQ) * DH;
  const bf16* Vbase = V + (size_t)((b * KV_GROUPS + grp) * SEQ) * DH;

  bf162 qp = *(const bf162*)(qrow + 2 * lane);
  q_lds[wave][2 * lane]     = __bfloat162float(qp.x);
  q_lds[wave][2 * lane + 1] = __bfloat162float(qp.y);
  // wave-private LDS region; compiler inserts lgkmcnt waits for RAW

  float m = -INFINITY, l = 0.f, o0 = 0.f, o1 = 0.f;
  int nkb = (s >> 6) + 1;
  for (int kb = 0; kb < nkb; kb++) {
    int j = kb * 64 + lane;                // this lane's key
    float sc = -INFINITY;
    if (j <= s) {
      const bf16* krow = Kbase + (size_t)j * DH;
      float accd = 0.f;
#pragma unroll
      for (int t = 0; t < 16; t++) {
        union { int4 v; bf16 hh[8]; } ku;
        ku.v = *(const int4*)(krow + t * 8);
#pragma unroll
        for (int uu = 0; uu < 8; uu++)
          accd += q_lds[wave][t * 8 + uu] * __bfloat162float(ku.hh[uu]);
      }
      sc = accd;   // q already scaled by 1/sqrt(Dh)
    }
    float mb = sc;
#pragma unroll
    for (int off = 1; off < 64; off <<= 1) mb = fmaxf(mb, __shfl_xor(mb, off));
    float m_new = fmaxf(m, mb);
    float alpha = __expf(m - m_new);       // m=-inf first iter -> alpha=0
    float p = (j <= s) ? __expf(sc - m_new) : 0.f;
    float ps = p;
#pragma unroll
    for (int off = 1; off < 64; off <<= 1) ps += __shfl_xor(ps, off);
    l = l * alpha + ps;
    o0 *= alpha; o1 *= alpha;
    m = m_new;
    const bf16* vb = Vbase + (size_t)(kb * 64) * DH;
#pragma unroll 8
    for (int j2 = 0; j2 < 64; j2++) {
      float pj = __shfl(p, j2);
      bf162 vv = *(const bf162*)(vb + (size_t)j2 * DH + 2 * lane);
      o0 += pj * __bfloat162float(vv.x);
      o1 += pj * __bfloat162float(vv.y);
    }
  }
  float inv = 1.f / l;
  // output layout (b, s, h, d) -> GEMM2 rows b*S+s, cols h*128+d
  bf16* orow = O + ((size_t)(b * SEQ + s) * NUM_HEADS + h) * DH;
  bf162 ov; ov.x = __float2bfloat16(o0 * inv); ov.y = __float2bfloat16(o1 * inv);
  *(bf162*)(orow + 2 * lane) = ov;
}

extern "C" void kernel_launch(void* const* d_in, const int* in_sizes, int n_in,
                              void* d_out, int out_size, void* d_ws, size_t ws_size,
                              hipStream_t stream) {
  const float* x  = (const float*)d_in[0];
  const float* wq = (const float*)d_in[1];
  const float* bq = (const float*)d_in[2];
  const float* wk = (const float*)d_in[3];
  const float* bk = (const float*)d_in[4];
  const float* wv = (const float*)d_in[5];
  const float* bv = (const float*)d_in[6];
  const float* wo = (const float*)d_in[7];
  const float* bo = (const float*)d_in[8];
  float* out = (float*)d_out;

  char* ws = (char*)d_ws;
  size_t off = 0;
  auto alloc = [&](size_t bytes) {
    void* p = ws + off;
    off += (bytes + 255) & ~(size_t)255;
    return p;
  };
  const size_t MS = (size_t)BATCH * SEQ;          // 8192
  bf16* Xb   = (bf16*)alloc(MS * FDIM * 2);                       // 32 MB
  bf16* Wqkv = (bf16*)alloc((size_t)FDIM * NQKV * 2);             // 12 MB
  bf16* Wo   = (bf16*)alloc((size_t)FDIM * FDIM * 2);             // 8 MB
  bf16* QKV  = (bf16*)alloc(MS * NQKV * 2);                       // 48 MB
  bf16* Qb   = (bf16*)alloc((size_t)BATCH * NUM_HEADS * SEQ * DH * 2);  // 32 MB
  bf16* Kb   = (bf16*)alloc((size_t)BATCH * KV_GROUPS * SEQ * DH * 2);  // 8 MB
  bf16* Vb   = (bf16*)alloc((size_t)BATCH * KV_GROUPS * SEQ * DH * 2);  // 8 MB
  bf16* Ob   = (bf16*)alloc(MS * FDIM * 2);                       // 32 MB

  int n4x = (int)(MS * FDIM / 4);
  cvt_f32_bf16<<<(n4x + 255) / 256, 256, 0, stream>>>(x, Xb, n4x);
  pack_wqkv<<<(FDIM * NQKV + 255) / 256, 256, 0, stream>>>(wq, wk, wv, Wqkv);
  int n4w = FDIM * FDIM / 4;
  cvt_f32_bf16<<<(n4w + 255) / 256, 256, 0, stream>>>(wo, Wo, n4w);

  dim3 g1(MS / 64, NQKV / 64);
  gemm64<1><<<g1, 256, 0, stream>>>(Xb, Wqkv, QKV, nullptr, (int)MS, NQKV, FDIM);

  rope_scatter<<<(int)(MS * 24 / 4), 256, 0, stream>>>(QKV, bq, bk, bv, Qb, Kb, Vb);

  attn_vec<<<(int)(BATCH * NUM_HEADS * SEQ / 4), 256, 0, stream>>>(Qb, Kb, Vb, Ob);

  dim3 g2(MS / 64, FDIM / 64);
  gemm64<0><<<g2, 256, 0, stream>>>(Ob, Wo, out, bo, (int)MS, FDIM, FDIM);
}

// Round 2
// 1363.033 us; speedup vs baseline: 4.2630x; 4.2630x over previous
//
#include <hip/hip_runtime.h>
#include <hip/hip_bf16.h>
#include <math.h>

using bf16 = __hip_bfloat16;
using bf162 = __hip_bfloat162;
typedef __attribute__((ext_vector_type(8))) short frag_ab;   // 8 bf16 (4 VGPRs)
typedef __attribute__((ext_vector_type(4))) float frag_cd;   // 4 fp32 acc

#define NUM_HEADS 16
#define KV_GROUPS 4
#define SEQ 2048
#define BATCH 4
#define FDIM 2048
#define DH 128
#define NQKV 3072   // H*DH + G*DH + G*DH

// ---------------- fp32 -> bf16 convert (vec4) ----------------
__global__ __launch_bounds__(256) void cvt_f32_bf16(const float* __restrict__ in,
                                                    bf16* __restrict__ out, int n4) {
  int i = blockIdx.x * 256 + threadIdx.x;
  if (i >= n4) return;
  float4 v = ((const float4*)in)[i];
  bf162 a; a.x = __float2bfloat16(v.x); a.y = __float2bfloat16(v.y);
  bf162 b; b.x = __float2bfloat16(v.z); b.y = __float2bfloat16(v.w);
  ((bf162*)out)[2 * i]     = a;
  ((bf162*)out)[2 * i + 1] = b;
}

// ---------------- pack [wq|wk|wv] -> (2048 x 3072) bf16 ----------------
__global__ __launch_bounds__(256) void pack_wqkv(const float* __restrict__ wq,
                                                 const float* __restrict__ wk,
                                                 const float* __restrict__ wv,
                                                 bf16* __restrict__ W) {
  int idx = blockIdx.x * 256 + threadIdx.x;
  if (idx >= FDIM * NQKV) return;
  int k = idx / NQKV, n = idx % NQKV;
  float v;
  if (n < 2048)       v = wq[(size_t)k * 2048 + n];
  else if (n < 2560)  v = wk[(size_t)k * 512 + (n - 2048)];
  else                v = wv[(size_t)k * 512 + (n - 2560)];
  W[idx] = __float2bfloat16(v);
}

// ---------------- bf16 MFMA GEMM: C[M,N] = A[M,K] * B[K,N] (+bias) ----------------
template <int OUTBF>
__global__ __launch_bounds__(256) void gemm64(const bf16* __restrict__ A,
                                              const bf16* __restrict__ B,
                                              void* __restrict__ Cout,
                                              const float* __restrict__ bias,
                                              int M, int N, int K) {
  __shared__ bf16 lds_a[64 * 32];    // [m][k]
  __shared__ bf16 lds_bT[64 * 32];   // [n][k]
  const int tid  = threadIdx.x;
  const int wave = tid >> 6, lane = tid & 63;
  const int quad = lane >> 4, l16 = lane & 15;
  const int m0 = blockIdx.x * 64, n0 = blockIdx.y * 64;

  frag_cd acc[4];
#pragma unroll
  for (int i = 0; i < 4; i++) acc[i] = (frag_cd){0.f, 0.f, 0.f, 0.f};

  const int ar = tid >> 2, ac = (tid & 3) * 8;
  const int br = tid >> 3, bc = (tid & 7) * 8;

  for (int k0 = 0; k0 < K; k0 += 32) {
    int4 av = *(const int4*)(A + (size_t)(m0 + ar) * K + (k0 + ac));
    int4 bv = *(const int4*)(B + (size_t)(k0 + br) * N + (n0 + bc));
    __syncthreads();
    *(int4*)&lds_a[ar * 32 + ac] = av;
    union { int4 v; bf16 h[8]; } u; u.v = bv;
#pragma unroll
    for (int i = 0; i < 8; i++) lds_bT[(bc + i) * 32 + br] = u.h[i];
    __syncthreads();
    frag_ab af = *(const frag_ab*)&lds_a[(wave * 16 + l16) * 32 + quad * 8];
#pragma unroll
    for (int nt = 0; nt < 4; nt++) {
      frag_ab bf = *(const frag_ab*)&lds_bT[(nt * 16 + l16) * 32 + quad * 8];
      acc[nt] = __builtin_amdgcn_mfma_f32_16x16x32_bf16(af, bf, acc[nt], 0, 0, 0);
    }
  }
#pragma unroll
  for (int nt = 0; nt < 4; nt++) {
#pragma unroll
    for (int r = 0; r < 4; r++) {
      int row = m0 + wave * 16 + quad * 4 + r;
      int col = n0 + nt * 16 + l16;
      float v = acc[nt][r];
      if (bias) v += bias[col];
      if (OUTBF) ((bf16*)Cout)[(size_t)row * N + col] = __float2bfloat16(v);
      else       ((float*)Cout)[(size_t)row * N + col] = v;
    }
  }
}

// ---------------- bias + RoPE + scale + scatter ----------------
__global__ __launch_bounds__(256) void rope_scatter(const bf16* __restrict__ qkv,
                                                    const float* __restrict__ bq,
                                                    const float* __restrict__ bk,
                                                    const float* __restrict__ bv,
                                                    bf16* __restrict__ Q,
                                                    bf16* __restrict__ K,
                                                    bf16* __restrict__ V) {
  int hrg  = blockIdx.x * 4 + (threadIdx.x >> 6);
  int lane = threadIdx.x & 63;
  int hr  = hrg % 24;
  int row = hrg / 24;
  int b = row >> 11, s = row & 2047;
  int kind, idx;
  if (hr < 16)      { kind = 0; idx = hr; }
  else if (hr < 20) { kind = 1; idx = hr - 16; }
  else              { kind = 2; idx = hr - 20; }
  int colbase = (kind == 0) ? idx * 128 : (kind == 1 ? 2048 + idx * 128 : 2560 + idx * 128);
  const bf16* src = qkv + (size_t)row * NQKV + colbase;
  bf162 xv = *(const bf162*)(src + 2 * lane);
  float a  = __bfloat162float(xv.x);
  float bb = __bfloat162float(xv.y);
  const float* bias = (kind == 0) ? bq : (kind == 1 ? bk : bv);
  a  += bias[idx * 128 + 2 * lane];
  bb += bias[idx * 128 + 2 * lane + 1];
  if (kind != 2 && lane < 32) {
    float freq = powf(10000.f, -(float)lane / 32.f);
    float ang  = (float)s * freq;
    float c = cosf(ang), sn = sinf(ang);
    float na = a * c - bb * sn;
    float nb = bb * c + a * sn;
    a = na; bb = nb;
  }
  if (kind == 0) { a *= 0.08838834764831845f; bb *= 0.08838834764831845f; }
  bf16* dst;
  if (kind == 0)      dst = Q + ((size_t)((b * NUM_HEADS + idx) * SEQ + s)) * DH;
  else if (kind == 1) dst = K + ((size_t)((b * KV_GROUPS + idx) * SEQ + s)) * DH;
  else                dst = V + ((size_t)((b * KV_GROUPS + idx) * SEQ + s)) * DH;
  bf162 ov; ov.x = __float2bfloat16(a); ov.y = __float2bfloat16(bb);
  *(bf162*)(dst + 2 * lane) = ov;
}

// ---------------- MFMA flash attention ----------------
// Block = 4 waves, one (b,h,64-row Q-tile). Wave w owns q-rows [q0+16w, q0+16w+16).
// Per 64-key KV tile: S = Q*K^T (MFMA), online softmax in C-layout, P via
// wave-private LDS transpose to A-layout, O += P*V (MFMA, V^T staged in LDS).
#define KSTRIDE 136   // 64x128 K tile, pad 128->136 (272B rows: bank-uniform, 16B-aligned)
#define VSTRIDE 72    // 128x64 V^T tile, pad 64->72 (144B rows)
#define PSTRIDE 72
__global__ __launch_bounds__(256) void attn_mfma(const bf16* __restrict__ Q,
                                                 const bf16* __restrict__ K,
                                                 const bf16* __restrict__ V,
                                                 bf16* __restrict__ O) {
  __shared__ bf16 k_lds[64 * KSTRIDE];    // [key][dim]
  __shared__ bf16 vt_lds[128 * VSTRIDE]; // [dim][key]
  __shared__ bf16 p_lds[4][16 * PSTRIDE]; // per-wave [qrow][key]

  const int tid = threadIdx.x;
  const int wave = tid >> 6, lane = tid & 63;
  const int quad = lane >> 4, l16 = lane & 15;

  const int bh   = blockIdx.x >> 5;
  const int tile = 31 - (blockIdx.x & 31);   // biggest trip counts dispatched first
  const int h = bh & 15, b = bh >> 4;
  const int grp = h >> 2;
  const int q0 = tile * 64;

  const bf16* Qbase = Q + ((size_t)(b * NUM_HEADS + h) * SEQ + q0 + wave * 16 + l16) * DH;
  const bf16* Kbase = K + ((size_t)(b * KV_GROUPS + grp) * SEQ) * DH;
  const bf16* Vbase = V + ((size_t)(b * KV_GROUPS + grp) * SEQ) * DH;

  // Q fragments (A-layout), resident for whole kernel
  frag_ab qf[4];
#pragma unroll
  for (int kt = 0; kt < 4; kt++)
    qf[kt] = *(const frag_ab*)(Qbase + kt * 32 + quad * 8);

  frag_cd oacc[8];
#pragma unroll
  for (int t = 0; t < 8; t++) oacc[t] = (frag_cd){0.f, 0.f, 0.f, 0.f};
  float m4[4], l4[4];
#pragma unroll
  for (int r = 0; r < 4; r++) { m4[r] = -1e30f; l4[r] = 0.f; }

  // staging index precompute
  const int srow = tid >> 2, scol = (tid & 3) * 32;  // K tile
  const int vkey = tid & 63, vd0 = (tid >> 6) * 8;   // V tile

  const int nkb = tile + 1;
  for (int kb = 0; kb < nkb; kb++) {
    __syncthreads();   // previous iteration's LDS reads done
    // ---- stage K [64][128] -> k_lds (row-major, padded) ----
    const bf16* Kt = Kbase + (size_t)(kb * 64) * DH;
#pragma unroll
    for (int it = 0; it < 4; it++) {
      int4 v = *(const int4*)(Kt + (size_t)srow * DH + scol + it * 8);
      *(int4*)&k_lds[srow * KSTRIDE + scol + it * 8] = v;
    }
    // ---- stage V [64][128] -> vt_lds transposed [dim][key] ----
    const bf16* Vt = Vbase + (size_t)(kb * 64) * DH;
#pragma unroll
    for (int it = 0; it < 4; it++) {
      int d = vd0 + it * 32;
      union { int4 v; bf16 hh[8]; } u;
      u.v = *(const int4*)(Vt + (size_t)vkey * DH + d);
#pragma unroll
      for (int uu = 0; uu < 8; uu++)
        vt_lds[(d + uu) * VSTRIDE + vkey] = u.hh[uu];  // 64 lanes consecutive keys: conflict-free
    }
    __syncthreads();

    // ---- S = Q * K^T : 4 key-subtiles x 4 k-chunks ----
    frag_cd sacc[4];
#pragma unroll
    for (int nt = 0; nt < 4; nt++) sacc[nt] = (frag_cd){0.f, 0.f, 0.f, 0.f};
#pragma unroll
    for (int nt = 0; nt < 4; nt++) {
#pragma unroll
      for (int kt = 0; kt < 4; kt++) {
        frag_ab kf = *(const frag_ab*)&k_lds[(nt * 16 + l16) * KSTRIDE + kt * 32 + quad * 8];
        sacc[nt] = __builtin_amdgcn_mfma_f32_16x16x32_bf16(qf[kt], kf, sacc[nt], 0, 0, 0);
      }
    }
    // ---- causal mask on diagonal tile: key nt*16+l16 > qrow wave*16+quad*4+r ----
    if (kb == tile) {
#pragma unroll
      for (int nt = 0; nt < 4; nt++)
#pragma unroll
        for (int r = 0; r < 4; r++)
          if (nt * 16 + l16 > wave * 16 + quad * 4 + r) sacc[nt][r] = -1e30f;
    }
    // ---- online softmax (row = quad*4+r; reduce across l16 lanes) ----
#pragma unroll
    for (int r = 0; r < 4; r++) {
      float mx = fmaxf(fmaxf(sacc[0][r], sacc[1][r]), fmaxf(sacc[2][r], sacc[3][r]));
#pragma unroll
      for (int off = 1; off < 16; off <<= 1) mx = fmaxf(mx, __shfl_xor(mx, off));
      float mn = fmaxf(m4[r], mx);
      float alpha = __expf(m4[r] - mn);
      float ps = 0.f;
#pragma unroll
      for (int nt = 0; nt < 4; nt++) {
        float p = __expf(sacc[nt][r] - mn);
        sacc[nt][r] = p;
        ps += p;
      }
#pragma unroll
      for (int off = 1; off < 16; off <<= 1) ps += __shfl_xor(ps, off);
      l4[r] = l4[r] * alpha + ps;
      m4[r] = mn;
#pragma unroll
      for (int t = 0; t < 8; t++) oacc[t][r] *= alpha;
    }
    // ---- P: C-layout -> A-layout via wave-private LDS ----
#pragma unroll
    for (int nt = 0; nt < 4; nt++)
#pragma unroll
      for (int r = 0; r < 4; r++)
        p_lds[wave][(quad * 4 + r) * PSTRIDE + nt * 16 + l16] = __float2bfloat16(sacc[nt][r]);
    frag_ab pf[2];
#pragma unroll
    for (int kt2 = 0; kt2 < 2; kt2++)
      pf[kt2] = *(const frag_ab*)&p_lds[wave][l16 * PSTRIDE + kt2 * 32 + quad * 8];
    // ---- O += P * V ----
#pragma unroll
    for (int nt2 = 0; nt2 < 8; nt2++) {
#pragma unroll
      for (int kt2 = 0; kt2 < 2; kt2++) {
        frag_ab vf = *(const frag_ab*)&vt_lds[(nt2 * 16 + l16) * VSTRIDE + kt2 * 32 + quad * 8];
        oacc[nt2] = __builtin_amdgcn_mfma_f32_16x16x32_bf16(pf[kt2], vf, oacc[nt2], 0, 0, 0);
      }
    }
  }
  // ---- epilogue: O /= l, write (b, s, h, d) bf16 ----
  float inv[4];
#pragma unroll
  for (int r = 0; r < 4; r++) inv[r] = 1.f / l4[r];
#pragma unroll
  for (int nt2 = 0; nt2 < 8; nt2++) {
#pragma unroll
    for (int r = 0; r < 4; r++) {
      int srow_g = q0 + wave * 16 + quad * 4 + r;
      int col = h * DH + nt2 * 16 + l16;
      O[(size_t)(b * SEQ + srow_g) * FDIM + col] = __float2bfloat16(oacc[nt2][r] * inv[r]);
    }
  }
}

extern "C" void kernel_launch(void* const* d_in, const int* in_sizes, int n_in,
                              void* d_out, int out_size, void* d_ws, size_t ws_size,
                              hipStream_t stream) {
  const float* x  = (const float*)d_in[0];
  const float* wq = (const float*)d_in[1];
  const float* bq = (const float*)d_in[2];
  const float* wk = (const float*)d_in[3];
  const float* bk = (const float*)d_in[4];
  const float* wv = (const float*)d_in[5];
  const float* bv = (const float*)d_in[6];
  const float* wo = (const float*)d_in[7];
  const float* bo = (const float*)d_in[8];
  float* out = (float*)d_out;

  char* ws = (char*)d_ws;
  size_t off = 0;
  auto alloc = [&](size_t bytes) {
    void* p = ws + off;
    off += (bytes + 255) & ~(size_t)255;
    return p;
  };
  const size_t MS = (size_t)BATCH * SEQ;          // 8192
  bf16* Xb   = (bf16*)alloc(MS * FDIM * 2);
  bf16* Wqkv = (bf16*)alloc((size_t)FDIM * NQKV * 2);
  bf16* Wo   = (bf16*)alloc((size_t)FDIM * FDIM * 2);
  bf16* QKV  = (bf16*)alloc(MS * NQKV * 2);
  bf16* Qb   = (bf16*)alloc((size_t)BATCH * NUM_HEADS * SEQ * DH * 2);
  bf16* Kb   = (bf16*)alloc((size_t)BATCH * KV_GROUPS * SEQ * DH * 2);
  bf16* Vb   = (bf16*)alloc((size_t)BATCH * KV_GROUPS * SEQ * DH * 2);
  bf16* Ob   = (bf16*)alloc(MS * FDIM * 2);

  int n4x = (int)(MS * FDIM / 4);
  cvt_f32_bf16<<<(n4x + 255) / 256, 256, 0, stream>>>(x, Xb, n4x);
  pack_wqkv<<<(FDIM * NQKV + 255) / 256, 256, 0, stream>>>(wq, wk, wv, Wqkv);
  int n4w = FDIM * FDIM / 4;
  cvt_f32_bf16<<<(n4w + 255) / 256, 256, 0, stream>>>(wo, Wo, n4w);

  dim3 g1(MS / 64, NQKV / 64);
  gemm64<1><<<g1, 256, 0, stream>>>(Xb, Wqkv, QKV, nullptr, (int)MS, NQKV, FDIM);

  rope_scatter<<<(int)(MS * 24 / 4), 256, 0, stream>>>(QKV, bq, bk, bv, Qb, Kb, Vb);

  attn_mfma<<<BATCH * NUM_HEADS * (SEQ / 64), 256, 0, stream>>>(Qb, Kb, Vb, Ob);

  dim3 g2(MS / 64, FDIM / 64);
  gemm64<0><<<g2, 256, 0, stream>>>(Ob, Wo, out, bo, (int)MS, FDIM, FDIM);
}

// Round 3
// 813.682 us; speedup vs baseline: 7.1412x; 1.6751x over previous
//
#include <hip/hip_runtime.h>
#include <hip/hip_bf16.h>
#include <math.h>

using bf16 = __hip_bfloat16;
using bf162 = __hip_bfloat162;
typedef __attribute__((ext_vector_type(8))) short frag_ab;   // 8 bf16 (4 VGPRs)
typedef __attribute__((ext_vector_type(4))) float frag_cd;   // 4 fp32 acc

typedef const __attribute__((address_space(1))) void* gptr_t;
typedef __attribute__((address_space(3))) void* lptr_t;

#define NUM_HEADS 16
#define KV_GROUPS 4
#define SEQ 2048
#define BATCH 4
#define FDIM 2048
#define DH 128
#define NQKV 3072   // H*DH + G*DH + G*DH

// ---------------- fp32 -> bf16 convert (vec4) ----------------
__global__ __launch_bounds__(256) void cvt_f32_bf16(const float* __restrict__ in,
                                                    bf16* __restrict__ out, int n4) {
  int i = blockIdx.x * 256 + threadIdx.x;
  if (i >= n4) return;
  float4 v = ((const float4*)in)[i];
  bf162 a; a.x = __float2bfloat16(v.x); a.y = __float2bfloat16(v.y);
  bf162 b; b.x = __float2bfloat16(v.z); b.y = __float2bfloat16(v.w);
  ((bf162*)out)[2 * i]     = a;
  ((bf162*)out)[2 * i + 1] = b;
}

// ---------------- transpose + cvt: src fp32 [R][C] -> dst bf16 [C][R] ----------------
// dst row stride = R. 64x64 tiles, coalesced read and write, LDS pad +1.
__global__ __launch_bounds__(256) void transpose_cvt(const float* __restrict__ src,
                                                     bf16* __restrict__ dst,
                                                     int R, int C) {
  __shared__ float tile[64][65];
  const int ct = blockIdx.x, rt = blockIdx.y;
  const int t = threadIdx.x;
  const int c4 = (t & 15) * 4, r0 = t >> 4;
#pragma unroll
  for (int p = 0; p < 4; p++) {
    int r = r0 + p * 16;
    float4 v = *(const float4*)(src + (size_t)(rt * 64 + r) * C + ct * 64 + c4);
    tile[r][c4] = v.x; tile[r][c4 + 1] = v.y; tile[r][c4 + 2] = v.z; tile[r][c4 + 3] = v.w;
  }
  __syncthreads();
  const int cr = t >> 2, k0 = (t & 3) * 16;
  union { int4 v[2]; bf16 h[16]; } u;
#pragma unroll
  for (int i = 0; i < 16; i++) u.h[i] = __float2bfloat16(tile[k0 + i][cr]);
  bf16* d = dst + (size_t)(ct * 64 + cr) * R + rt * 64 + k0;
  *(int4*)d = u.v[0];
  *(int4*)(d + 8) = u.v[1];
}

// ---------------- m97-style bf16 MFMA GEMM: C[M,N] = A[M,K] * BT[N,K]^T ----------------
// 128x128 tile, BK=32, 4 waves each 64x64. Staging via global_load_lds width=16:
// unpadded [row][32] LDS layout (wave-uniform base + lane*16 constraint).
template <int OUTBF>
__global__ __launch_bounds__(256) void gemm128(const bf16* __restrict__ A,
                                               const bf16* __restrict__ BT,
                                               void* __restrict__ Cout,
                                               const float* __restrict__ bias,
                                               int M, int N, int K) {
  __shared__ bf16 a_lds[128 * 32];
  __shared__ bf16 b_lds[128 * 32];
  const int tid = threadIdx.x;
  const int wave = tid >> 6, lane = tid & 63;
  const int quad = lane >> 4, l16 = lane & 15;
  const int m0 = blockIdx.x * 128, n0 = blockIdx.y * 128;
  const int wm = (wave & 1) * 64, wn = (wave >> 1) * 64;

  frag_cd acc[4][4];
#pragma unroll
  for (int mt = 0; mt < 4; mt++)
#pragma unroll
    for (int nt = 0; nt < 4; nt++) acc[mt][nt] = (frag_cd){0.f, 0.f, 0.f, 0.f};

  // staging segments: seg in [0,512), 8 bf16 each; row = seg>>2, koff = (seg&3)*8
  const int seg0 = wave * 64 + lane;
  const int seg1 = (4 + wave) * 64 + lane;
  const bf16* aP0 = A  + (size_t)(m0 + (seg0 >> 2)) * K + (seg0 & 3) * 8;
  const bf16* aP1 = A  + (size_t)(m0 + (seg1 >> 2)) * K + (seg1 & 3) * 8;
  const bf16* bP0 = BT + (size_t)(n0 + (seg0 >> 2)) * K + (seg0 & 3) * 8;
  const bf16* bP1 = BT + (size_t)(n0 + (seg1 >> 2)) * K + (seg1 & 3) * 8;
  bf16* aL0 = &a_lds[(size_t)wave * 64 * 8];
  bf16* aL1 = &a_lds[(size_t)(4 + wave) * 64 * 8];
  bf16* bL0 = &b_lds[(size_t)wave * 64 * 8];
  bf16* bL1 = &b_lds[(size_t)(4 + wave) * 64 * 8];

  for (int k0 = 0; k0 < K; k0 += 32) {
    __syncthreads();   // previous iteration's LDS reads done
    __builtin_amdgcn_global_load_lds((gptr_t)(aP0 + k0), (lptr_t)aL0, 16, 0, 0);
    __builtin_amdgcn_global_load_lds((gptr_t)(aP1 + k0), (lptr_t)aL1, 16, 0, 0);
    __builtin_amdgcn_global_load_lds((gptr_t)(bP0 + k0), (lptr_t)bL0, 16, 0, 0);
    __builtin_amdgcn_global_load_lds((gptr_t)(bP1 + k0), (lptr_t)bL1, 16, 0, 0);
    __syncthreads();   // drains vmcnt(0): staged data visible

    frag_ab af[4], bfr[4];
#pragma unroll
    for (int mt = 0; mt < 4; mt++)
      af[mt] = *(const frag_ab*)&a_lds[(wm + mt * 16 + l16) * 32 + quad * 8];
#pragma unroll
    for (int nt = 0; nt < 4; nt++)
      bfr[nt] = *(const frag_ab*)&b_lds[(wn + nt * 16 + l16) * 32 + quad * 8];
#pragma unroll
    for (int mt = 0; mt < 4; mt++)
#pragma unroll
      for (int nt = 0; nt < 4; nt++)
        acc[mt][nt] = __builtin_amdgcn_mfma_f32_16x16x32_bf16(af[mt], bfr[nt], acc[mt][nt], 0, 0, 0);
  }

  // C/D layout: col = l16, row = quad*4 + r
#pragma unroll
  for (int mt = 0; mt < 4; mt++) {
#pragma unroll
    for (int nt = 0; nt < 4; nt++) {
#pragma unroll
      for (int r = 0; r < 4; r++) {
        int row = m0 + wm + mt * 16 + quad * 4 + r;
        int col = n0 + wn + nt * 16 + l16;
        float v = acc[mt][nt][r];
        if (bias) v += bias[col];
        if (OUTBF) ((bf16*)Cout)[(size_t)row * N + col] = __float2bfloat16(v);
        else       ((float*)Cout)[(size_t)row * N + col] = v;
      }
    }
  }
}

// ---------------- bias + RoPE + scale + scatter ----------------
__global__ __launch_bounds__(256) void rope_scatter(const bf16* __restrict__ qkv,
                                                    const float* __restrict__ bq,
                                                    const float* __restrict__ bk,
                                                    const float* __restrict__ bv,
                                                    bf16* __restrict__ Q,
                                                    bf16* __restrict__ K,
                                                    bf16* __restrict__ V) {
  int hrg  = blockIdx.x * 4 + (threadIdx.x >> 6);
  int lane = threadIdx.x & 63;
  int hr  = hrg % 24;
  int row = hrg / 24;
  int b = row >> 11, s = row & 2047;
  int kind, idx;
  if (hr < 16)      { kind = 0; idx = hr; }
  else if (hr < 20) { kind = 1; idx = hr - 16; }
  else              { kind = 2; idx = hr - 20; }
  int colbase = (kind == 0) ? idx * 128 : (kind == 1 ? 2048 + idx * 128 : 2560 + idx * 128);
  const bf16* src = qkv + (size_t)row * NQKV + colbase;
  bf162 xv = *(const bf162*)(src + 2 * lane);
  float a  = __bfloat162float(xv.x);
  float bb = __bfloat162float(xv.y);
  const float* bias = (kind == 0) ? bq : (kind == 1 ? bk : bv);
  a  += bias[idx * 128 + 2 * lane];
  bb += bias[idx * 128 + 2 * lane + 1];
  if (kind != 2 && lane < 32) {
    float freq = powf(10000.f, -(float)lane / 32.f);
    float ang  = (float)s * freq;
    float c = cosf(ang), sn = sinf(ang);
    float na = a * c - bb * sn;
    float nb = bb * c + a * sn;
    a = na; bb = nb;
  }
  if (kind == 0) { a *= 0.08838834764831845f; bb *= 0.08838834764831845f; }
  bf16* dst;
  if (kind == 0)      dst = Q + ((size_t)((b * NUM_HEADS + idx) * SEQ + s)) * DH;
  else if (kind == 1) dst = K + ((size_t)((b * KV_GROUPS + idx) * SEQ + s)) * DH;
  else                dst = V + ((size_t)((b * KV_GROUPS + idx) * SEQ + s)) * DH;
  bf162 ov; ov.x = __float2bfloat16(a); ov.y = __float2bfloat16(bb);
  *(bf162*)(dst + 2 * lane) = ov;
}

// ---------------- MFMA flash attention ----------------
#define KSTRIDE 136
#define VSTRIDE 72
#define PSTRIDE 72
__global__ __launch_bounds__(256) void attn_mfma(const bf16* __restrict__ Q,
                                                 const bf16* __restrict__ K,
                                                 const bf16* __restrict__ V,
                                                 bf16* __restrict__ O) {
  __shared__ bf16 k_lds[64 * KSTRIDE];
  __shared__ bf16 vt_lds[128 * VSTRIDE];
  __shared__ bf16 p_lds[4][16 * PSTRIDE];

  const int tid = threadIdx.x;
  const int wave = tid >> 6, lane = tid & 63;
  const int quad = lane >> 4, l16 = lane & 15;

  const int bh   = blockIdx.x >> 5;
  const int tile = 31 - (blockIdx.x & 31);
  const int h = bh & 15, b = bh >> 4;
  const int grp = h >> 2;
  const int q0 = tile * 64;

  const bf16* Qbase = Q + ((size_t)(b * NUM_HEADS + h) * SEQ + q0 + wave * 16 + l16) * DH;
  const bf16* Kbase = K + ((size_t)(b * KV_GROUPS + grp) * SEQ) * DH;
  const bf16* Vbase = V + ((size_t)(b * KV_GROUPS + grp) * SEQ) * DH;

  frag_ab qf[4];
#pragma unroll
  for (int kt = 0; kt < 4; kt++)
    qf[kt] = *(const frag_ab*)(Qbase + kt * 32 + quad * 8);

  frag_cd oacc[8];
#pragma unroll
  for (int t = 0; t < 8; t++) oacc[t] = (frag_cd){0.f, 0.f, 0.f, 0.f};
  float m4[4], l4[4];
#pragma unroll
  for (int r = 0; r < 4; r++) { m4[r] = -1e30f; l4[r] = 0.f; }

  const int srow = tid >> 2, scol = (tid & 3) * 32;
  const int vkey = tid & 63, vd0 = (tid >> 6) * 8;

  const int nkb = tile + 1;
  for (int kb = 0; kb < nkb; kb++) {
    __syncthreads();
    const bf16* Kt = Kbase + (size_t)(kb * 64) * DH;
#pragma unroll
    for (int it = 0; it < 4; it++) {
      int4 v = *(const int4*)(Kt + (size_t)srow * DH + scol + it * 8);
      *(int4*)&k_lds[srow * KSTRIDE + scol + it * 8] = v;
    }
    const bf16* Vt = Vbase + (size_t)(kb * 64) * DH;
#pragma unroll
    for (int it = 0; it < 4; it++) {
      int d = vd0 + it * 32;
      union { int4 v; bf16 hh[8]; } u;
      u.v = *(const int4*)(Vt + (size_t)vkey * DH + d);
#pragma unroll
      for (int uu = 0; uu < 8; uu++)
        vt_lds[(d + uu) * VSTRIDE + vkey] = u.hh[uu];
    }
    __syncthreads();

    frag_cd sacc[4];
#pragma unroll
    for (int nt = 0; nt < 4; nt++) sacc[nt] = (frag_cd){0.f, 0.f, 0.f, 0.f};
#pragma unroll
    for (int nt = 0; nt < 4; nt++) {
#pragma unroll
      for (int kt = 0; kt < 4; kt++) {
        frag_ab kf = *(const frag_ab*)&k_lds[(nt * 16 + l16) * KSTRIDE + kt * 32 + quad * 8];
        sacc[nt] = __builtin_amdgcn_mfma_f32_16x16x32_bf16(qf[kt], kf, sacc[nt], 0, 0, 0);
      }
    }
    if (kb == tile) {
#pragma unroll
      for (int nt = 0; nt < 4; nt++)
#pragma unroll
        for (int r = 0; r < 4; r++)
          if (nt * 16 + l16 > wave * 16 + quad * 4 + r) sacc[nt][r] = -1e30f;
    }
#pragma unroll
    for (int r = 0; r < 4; r++) {
      float mx = fmaxf(fmaxf(sacc[0][r], sacc[1][r]), fmaxf(sacc[2][r], sacc[3][r]));
#pragma unroll
      for (int off = 1; off < 16; off <<= 1) mx = fmaxf(mx, __shfl_xor(mx, off));
      float mn = fmaxf(m4[r], mx);
      float alpha = __expf(m4[r] - mn);
      float ps = 0.f;
#pragma unroll
      for (int nt = 0; nt < 4; nt++) {
        float p = __expf(sacc[nt][r] - mn);
        sacc[nt][r] = p;
        ps += p;
      }
#pragma unroll
      for (int off = 1; off < 16; off <<= 1) ps += __shfl_xor(ps, off);
      l4[r] = l4[r] * alpha + ps;
      m4[r] = mn;
#pragma unroll
      for (int t = 0; t < 8; t++) oacc[t][r] *= alpha;
    }
#pragma unroll
    for (int nt = 0; nt < 4; nt++)
#pragma unroll
      for (int r = 0; r < 4; r++)
        p_lds[wave][(quad * 4 + r) * PSTRIDE + nt * 16 + l16] = __float2bfloat16(sacc[nt][r]);
    frag_ab pf[2];
#pragma unroll
    for (int kt2 = 0; kt2 < 2; kt2++)
      pf[kt2] = *(const frag_ab*)&p_lds[wave][l16 * PSTRIDE + kt2 * 32 + quad * 8];
#pragma unroll
    for (int nt2 = 0; nt2 < 8; nt2++) {
#pragma unroll
      for (int kt2 = 0; kt2 < 2; kt2++) {
        frag_ab vf = *(const frag_ab*)&vt_lds[(nt2 * 16 + l16) * VSTRIDE + kt2 * 32 + quad * 8];
        oacc[nt2] = __builtin_amdgcn_mfma_f32_16x16x32_bf16(pf[kt2], vf, oacc[nt2], 0, 0, 0);
      }
    }
  }
  float inv[4];
#pragma unroll
  for (int r = 0; r < 4; r++) inv[r] = 1.f / l4[r];
#pragma unroll
  for (int nt2 = 0; nt2 < 8; nt2++) {
#pragma unroll
    for (int r = 0; r < 4; r++) {
      int srow_g = q0 + wave * 16 + quad * 4 + r;
      int col = h * DH + nt2 * 16 + l16;
      O[(size_t)(b * SEQ + srow_g) * FDIM + col] = __float2bfloat16(oacc[nt2][r] * inv[r]);
    }
  }
}

extern "C" void kernel_launch(void* const* d_in, const int* in_sizes, int n_in,
                              void* d_out, int out_size, void* d_ws, size_t ws_size,
                              hipStream_t stream) {
  const float* x  = (const float*)d_in[0];
  const float* wq = (const float*)d_in[1];
  const float* bq = (const float*)d_in[2];
  const float* wk = (const float*)d_in[3];
  const float* bk = (const float*)d_in[4];
  const float* wv = (const float*)d_in[5];
  const float* bv = (const float*)d_in[6];
  const float* wo = (const float*)d_in[7];
  const float* bo = (const float*)d_in[8];
  float* out = (float*)d_out;

  char* ws = (char*)d_ws;
  size_t off = 0;
  auto alloc = [&](size_t bytes) {
    void* p = ws + off;
    off += (bytes + 255) & ~(size_t)255;
    return p;
  };
  const size_t MS = (size_t)BATCH * SEQ;          // 8192
  bf16* Xb    = (bf16*)alloc(MS * FDIM * 2);
  bf16* WqkvT = (bf16*)alloc((size_t)NQKV * FDIM * 2);   // [n][k], n<3072, k<2048
  bf16* WoT   = (bf16*)alloc((size_t)FDIM * FDIM * 2);   // [f][hd]
  bf16* QKV   = (bf16*)alloc(MS * NQKV * 2);
  bf16* Qb    = (bf16*)alloc((size_t)BATCH * NUM_HEADS * SEQ * DH * 2);
  bf16* Kb    = (bf16*)alloc((size_t)BATCH * KV_GROUPS * SEQ * DH * 2);
  bf16* Vb    = (bf16*)alloc((size_t)BATCH * KV_GROUPS * SEQ * DH * 2);
  bf16* Ob    = (bf16*)alloc(MS * FDIM * 2);

  int n4x = (int)(MS * FDIM / 4);
  cvt_f32_bf16<<<(n4x + 255) / 256, 256, 0, stream>>>(x, Xb, n4x);

  // weights: fp32 [K][N] -> bf16 [N][K]
  transpose_cvt<<<dim3(2048 / 64, 2048 / 64), 256, 0, stream>>>(wq, WqkvT, 2048, 2048);
  transpose_cvt<<<dim3(512 / 64, 2048 / 64), 256, 0, stream>>>(wk, WqkvT + (size_t)2048 * 2048, 2048, 512);
  transpose_cvt<<<dim3(512 / 64, 2048 / 64), 256, 0, stream>>>(wv, WqkvT + (size_t)2560 * 2048, 2048, 512);
  transpose_cvt<<<dim3(2048 / 64, 2048 / 64), 256, 0, stream>>>(wo, WoT, 2048, 2048);

  dim3 g1(MS / 128, NQKV / 128);
  gemm128<1><<<g1, 256, 0, stream>>>(Xb, WqkvT, QKV, nullptr, (int)MS, NQKV, FDIM);

  rope_scatter<<<(int)(MS * 24 / 4), 256, 0, stream>>>(QKV, bq, bk, bv, Qb, Kb, Vb);

  attn_mfma<<<BATCH * NUM_HEADS * (SEQ / 64), 256, 0, stream>>>(Qb, Kb, Vb, Ob);

  dim3 g2(MS / 128, FDIM / 128);
  gemm128<0><<<g2, 256, 0, stream>>>(Ob, WoT, out, bo, (int)MS, FDIM, FDIM);
}